// Round 6
// baseline (165.815 us; speedup 1.0000x reference)
//
#include <hip/hip_runtime.h>
#include <math.h>

#define L 256
#define E 128
#define H 4
#define C 32
#define P (L*L)  // 65536

typedef __bf16 bf16;
typedef __bf16 bf16x8 __attribute__((ext_vector_type(8)));
typedef __bf16 bf16x4 __attribute__((ext_vector_type(4)));
typedef float  f32x4  __attribute__((ext_vector_type(4)));

#define MFMA(a,b,c) __builtin_amdgcn_mfma_f32_16x16x32_bf16((a),(b),(c),0,0,0)

// ---------------------------------------------------------------------------
// k_prep: emit weights in MFMA A-fragment order. Grid 41: blocks 0..39 cover
// (m, frag-quad) with one fragment per wave; block 40 builds WbF.
// ---------------------------------------------------------------------------
__global__ __launch_bounds__(256) void k_prep(
    const float* __restrict__ Wq, const float* __restrict__ Wk,
    const float* __restrict__ Wv, const float* __restrict__ Wfu,
    const float* __restrict__ Wo, const float* __restrict__ Wb,
    bf16* __restrict__ WF, bf16* __restrict__ WoF, bf16* __restrict__ WbF)
{
  const int b = blockIdx.x;  // 0..40
  const int lane = threadIdx.x & 63, wv = threadIdx.x >> 6;
  const int g = lane >> 4, l15 = lane & 15;
  if (b < 40) {
    const int m = b >> 3;
    const int f = (b & 7) * 4 + wv;
    const float* W = (m==0)?Wq:(m==1)?Wk:(m==2)?Wv:(m==3)?Wfu:Wo;
    bf16* dst = (m < 4) ? (WF + (size_t)m * 16384) : WoF;
    const float sc = (m == 0) ? 0.17677669529663689f : 1.0f;
    const int mt = f >> 2, kt = f & 3;
    const int row = 16*mt + l15, k0 = 32*kt + 8*g;
    bf16x8 o;
    #pragma unroll
    for (int j = 0; j < 8; ++j) o[j] = (bf16)(W[(size_t)(k0+j)*128 + row] * sc);
    *(bf16x8*)(dst + ((size_t)f*64 + lane)*8) = o;
  } else {
    const int kt = wv, k0 = 32*kt + 8*g;
    bf16x8 o;
    #pragma unroll
    for (int j = 0; j < 8; ++j)
      o[j] = (l15 < 4) ? (bf16)Wb[(size_t)(k0+j)*4 + l15] : (bf16)0.0f;
    *(bf16x8*)(WbF + ((size_t)kt*64 + lane)*8) = o;
  }
}

// ---------------------------------------------------------------------------
// k_ln_proj: 512 threads = 8 waves; wave (m = w&3, half = w>>2) computes the
// half-matrix mt in [4*half, 4*half+4) of matrix m. 16 pinned weight frags
// per wave; LN 8 threads/position. (unchanged from round 5)
// ---------------------------------------------------------------------------
__global__ __launch_bounds__(512) void k_ln_proj(
    const float* __restrict__ pr, const float* __restrict__ gamma,
    const float* __restrict__ beta, const float* __restrict__ bfu,
    const bf16* __restrict__ WF, const bf16* __restrict__ WbF,
    bf16* __restrict__ qbh, bf16* __restrict__ kbh, bf16* __restrict__ vbh,
    bf16* __restrict__ gfb, float* __restrict__ pbo)
{
  __shared__ bf16 xs[64 * 136];        // 17.0 KB
  __shared__ bf16 stag[4][16 * 136];   // 17.0 KB
  const int tid = threadIdx.x;
  const int base = blockIdx.x * 64;
  const int w = tid >> 6, lane = tid & 63, g = lane >> 4, l15 = lane & 15;
  const int m = w & 3, half = w >> 2;

  const bf16* WFw = WF + (size_t)m * 16384 + (size_t)half * 8192;
  f32x4 af[16];
  #pragma unroll
  for (int f = 0; f < 16; ++f)
    af[f] = *(const f32x4*)(WFw + ((size_t)f*64 + lane)*8);

  // --- LayerNorm (8 threads per position, 16 floats each) ---
  {
    const int pl = tid >> 3, sub = tid & 7;
    const float4* src = (const float4*)(pr + (size_t)(base + pl) * 128 + sub * 16);
    float4 r[4];
    float s = 0.f, ss = 0.f;
    #pragma unroll
    for (int j = 0; j < 4; ++j) {
      r[j] = src[j];
      s  += r[j].x + r[j].y + r[j].z + r[j].w;
      ss += r[j].x*r[j].x + r[j].y*r[j].y + r[j].z*r[j].z + r[j].w*r[j].w;
    }
    s  += __shfl_xor(s, 1, 8);  s  += __shfl_xor(s, 2, 8);  s  += __shfl_xor(s, 4, 8);
    ss += __shfl_xor(ss, 1, 8); ss += __shfl_xor(ss, 2, 8); ss += __shfl_xor(ss, 4, 8);
    const float mu   = s * 0.0078125f;
    const float var  = ss * 0.0078125f - mu * mu;
    const float rstd = rsqrtf(var + 1e-5f);
    const float4* g4 = (const float4*)(gamma + sub * 16);
    const float4* b4 = (const float4*)(beta + sub * 16);
    bf16* xr = xs + pl * 136 + sub * 16;
    #pragma unroll
    for (int i = 0; i < 2; ++i) {
      float4 r0 = r[2*i], r1 = r[2*i+1];
      float4 gg0 = g4[2*i], gg1 = g4[2*i+1], bb0 = b4[2*i], bb1 = b4[2*i+1];
      bf16x8 o;
      o[0] = (bf16)((r0.x - mu) * rstd * gg0.x + bb0.x);
      o[1] = (bf16)((r0.y - mu) * rstd * gg0.y + bb0.y);
      o[2] = (bf16)((r0.z - mu) * rstd * gg0.z + bb0.z);
      o[3] = (bf16)((r0.w - mu) * rstd * gg0.w + bb0.w);
      o[4] = (bf16)((r1.x - mu) * rstd * gg1.x + bb1.x);
      o[5] = (bf16)((r1.y - mu) * rstd * gg1.y + bb1.y);
      o[6] = (bf16)((r1.z - mu) * rstd * gg1.z + bb1.z);
      o[7] = (bf16)((r1.w - mu) * rstd * gg1.w + bb1.w);
      *(bf16x8*)(xr + 8 * i) = o;
    }
  }

  #pragma unroll
  for (int f = 0; f < 16; ++f)
    asm volatile("" : "+v"(af[f]));

  __syncthreads();

  const f32x4 z = {0.f, 0.f, 0.f, 0.f};

  if (w < 4) {
    f32x4 acc = z;
    #pragma unroll
    for (int kt = 0; kt < 4; ++kt) {
      bf16x8 a = *(const bf16x8*)(WbF + ((size_t)kt*64 + lane)*8);
      bf16x8 b = *(const bf16x8*)(xs + (16*w + l15)*136 + 32*kt + 8*g);
      acc = MFMA(a, b, acc);
    }
    if (g == 0)
      *(float4*)(pbo + (size_t)(base + 16*w + l15)*4) =
          make_float4(acc[0], acc[1], acc[2], acc[3]);
  }

  bf16* stw = stag[m];

  for (int nt = 0; nt < 4; ++nt) {
    bf16x8 bfr[4];
    #pragma unroll
    for (int kt = 0; kt < 4; ++kt)
      bfr[kt] = *(const bf16x8*)(xs + (16*nt + l15)*136 + 32*kt + 8*g);
    f32x4 acc[4];
    #pragma unroll
    for (int mtl = 0; mtl < 4; ++mtl) acc[mtl] = z;
    #pragma unroll
    for (int kt = 0; kt < 4; ++kt)
      #pragma unroll
      for (int mtl = 0; mtl < 4; ++mtl)
        acc[mtl] = MFMA(__builtin_bit_cast(bf16x8, af[mtl*4 + kt]), bfr[kt], acc[mtl]);

    #pragma unroll
    for (int mtl = 0; mtl < 4; ++mtl) {
      const int col = half*64 + 16*mtl + 4*g;
      f32x4 vv = acc[mtl];
      if (m == 3) {
        float4 bb = *(const float4*)(bfu + col);
        vv[0] = 1.f / (1.f + __expf(-(vv[0] + bb.x)));
        vv[1] = 1.f / (1.f + __expf(-(vv[1] + bb.y)));
        vv[2] = 1.f / (1.f + __expf(-(vv[2] + bb.z)));
        vv[3] = 1.f / (1.f + __expf(-(vv[3] + bb.w)));
      }
      bf16x4 o;
      o[0] = (bf16)vv[0]; o[1] = (bf16)vv[1]; o[2] = (bf16)vv[2]; o[3] = (bf16)vv[3];
      *(bf16x4*)(stw + l15*136 + col) = o;
    }

    #pragma unroll
    for (int i = 0; i < 2; ++i) {
      const int flat = i*512 + lane*8;
      const int p = flat >> 6, cf = half*64 + (flat & 63);
      bf16x8 val = *(const bf16x8*)(stw + p*136 + cf);
      if (m == 3) {
        *(bf16x8*)(gfb + ((size_t)(base + 16*nt + p))*128 + cf) = val;
      } else {
        bf16* dst = (m == 0) ? qbh : (m == 1) ? kbh : vbh;
        const int h = cf >> 5;
        *(bf16x8*)(dst + ((size_t)h*P + base + 16*nt + p)*32 + (cf & 31)) = val;
      }
    }
  }
}

// ---------------------------------------------------------------------------
// k_bias: T5[h][q][v] = mask[q,v] + pb[q,v,h]  (bf16). grid 256 (q), 256 thr.
// ---------------------------------------------------------------------------
__global__ __launch_bounds__(256) void k_bias(
    const float* __restrict__ mask, const float* __restrict__ pb,
    bf16* __restrict__ T5)
{
  const int q = blockIdx.x;
  const int v = threadIdx.x;
  const size_t qv = (size_t)q*256 + v;
  const float m = mask[qv];
  float4 p = *(const float4*)(pb + qv*4);
  T5[qv]            = (bf16)(m + p.x);
  T5[qv +   65536]  = (bf16)(m + p.y);
  T5[qv + 2*65536]  = (bf16)(m + p.z);
  T5[qv + 3*65536]  = (bf16)(m + p.w);
}

// ---------------------------------------------------------------------------
// k_attn_gate: FUSION of attention + gate + Wo. Grid 512 = (s, qhalf);
// 512 threads = 8 waves x 16 q-rows. Per head h: stage q-proj (slot-permuted)
// + vT (swizzled) -> QK^T/softmax/PV (P lane-local, as before) -> multiply by
// the gate slice (cols 32h..32h+31 of gfb) in-register -> deposit gated bf16
// into gs LDS. After 4 heads: one barrier, then out = gs @ Wo + bo per wave
// (wave = 16-col group). Eliminates the aob HBM round-trip (33.6 MB) and the
// entire k_gate_out kernel (launch + prologue + re-reads).
// LDS: 20 + 16.5 + 34 = 70.5 KB -> 2 blocks/CU.
// ---------------------------------------------------------------------------
__global__ __launch_bounds__(512) void k_attn_gate(
    const bf16* __restrict__ qbh, const bf16* __restrict__ kbh,
    const bf16* __restrict__ vbh, const bf16* __restrict__ T5,
    const bf16* __restrict__ gfb, const bf16* __restrict__ WoF,
    const float* __restrict__ bo, float* __restrict__ out)
{
  __shared__ bf16 qs[256 * 40];    // 20.0 KB, slot-permuted q-projection
  __shared__ bf16 vT[32 * 264];    // 16.5 KB, swizzled V^T
  __shared__ bf16 gs[128 * 136];   // 34.0 KB, gated attention output
  const int tid = threadIdx.x;     // 0..511
  const int s = blockIdx.x >> 1, hf = blockIdx.x & 1;
  const int rb = s * 256;
  const int w = tid >> 6, lane = tid & 63, g = lane >> 4, l15 = lane & 15;
  const int ql = hf*128 + w*16 + l15;   // this lane's q row within s [0,256)

  const f32x4 z = {0.f, 0.f, 0.f, 0.f};

  for (int h = 0; h < 4; ++h) {
    if (h) __syncthreads();   // all waves done reading qs/vT of head h-1

    const bf16* qh = qbh + (size_t)h * P * 32;
    const bf16* kh = kbh + (size_t)h * P * 32;
    const bf16* vh = vbh + (size_t)h * P * 32;

    // k-row B-fragment for this wave's q-tile (global; overlaps staging)
    bf16x8 bq = *(const bf16x8*)(kh + ((size_t)rb + ql)*32 + 8*g);

    // stage q (slot-permuted rows, stride 40) and vT (swizzled transpose)
    #pragma unroll
    for (int i = 0; i < 2; ++i) {
      const int flat = i*4096 + tid*8;
      const int pos = flat >> 5, cc = flat & 31;
      // sigma: pos bits [7:5]=kt [4:3]=c2 [2]=half [1:0]=m -> slot bits
      //        [7:5]=kt [4]=half [3:2]=c2 [1:0]=m
      const int slot = (pos & 0xE3) | ((pos & 0x04) << 2) | ((pos & 0x18) >> 1);
      bf16x8 qv = *(const bf16x8*)(qh + ((size_t)rb + pos)*32 + cc);
      *(bf16x8*)(qs + slot*40 + cc) = qv;
      bf16x8 vv = *(const bf16x8*)(vh + ((size_t)rb + pos)*32 + cc);
      #pragma unroll
      for (int j = 0; j < 8; ++j) {
        const int row = cc + j;
        const int a = row >> 3;
        const int X = (a << 5) | ((a >> 1) << 4);
        vT[row*264 + (pos ^ X)] = vv[j];
      }
    }
    __syncthreads();

    // vT read swizzle constants for the two PV A-rows this lane uses
    const int a0r = l15 >> 3;
    const int X0 = (a0r << 5) | ((a0r >> 1) << 4);
    const int a1r = (16 + l15) >> 3;
    const int X1 = (a1r << 5) | ((a1r >> 1) << 4);

    const bf16* Trow = T5 + (size_t)h * 65536 + (size_t)ql * 256 + 8*g;
    f32x4 o0a = z, o0b = z, o1a = z, o1b = z;
    float rs = 0.f;
    #pragma unroll
    for (int kt = 0; kt < 8; ++kt) {
      bf16x8 a0 = *(const bf16x8*)(qs + (16*(2*kt + 0) + l15)*40 + 8*g);
      bf16x8 a1 = *(const bf16x8*)(qs + (16*(2*kt + 1) + l15)*40 + 8*g);
      f32x4 s0 = MFMA(a0, bq, z);
      f32x4 s1 = MFMA(a1, bq, z);
      bf16x4 b0 = *(const bf16x4*)(Trow + 32*kt);
      bf16x4 b1 = *(const bf16x4*)(Trow + 32*kt + 4);
      bf16x8 pf;
      #pragma unroll
      for (int r = 0; r < 4; ++r) {
        float e0 = __expf(s0[r] + (float)b0[r]);
        float e1 = __expf(s1[r] + (float)b1[r]);
        pf[r]     = (bf16)e0;
        pf[4 + r] = (bf16)e1;
        rs += e0 + e1;
      }
      // PV A-fragments read inline from swizzled vT (each used once)
      bf16x8 av0 = *(const bf16x8*)(vT + (l15)*264      + ((32*kt + 8*g) ^ X0));
      bf16x8 av1 = *(const bf16x8*)(vT + (16 + l15)*264 + ((32*kt + 8*g) ^ X1));
      if (kt & 1) {
        o0b = MFMA(av0, pf, o0b);
        o1b = MFMA(av1, pf, o1b);
      } else {
        o0a = MFMA(av0, pf, o0a);
        o1a = MFMA(av1, pf, o1a);
      }
    }
    rs += __shfl_xor(rs, 16);
    rs += __shfl_xor(rs, 32);
    const float inv = 1.f / rs;

    // gate slice for this lane's row: cols 32h+4g.. and 32h+16+4g..
    const bf16* grow = gfb + ((size_t)rb + ql)*128 + 32*h;
    bf16x4 g0 = *(const bf16x4*)(grow + 4*g);
    bf16x4 g1 = *(const bf16x4*)(grow + 16 + 4*g);

    bf16x4 p0, p1;
    #pragma unroll
    for (int r = 0; r < 4; ++r) {
      p0[r] = (bf16)((o0a[r] + o0b[r]) * inv * (float)g0[r]);
      p1[r] = (bf16)((o1a[r] + o1b[r]) * inv * (float)g1[r]);
    }
    // deposit gated output into gs (local row = w*16+l15, col = 32h + ...)
    bf16* gr = gs + (size_t)(w*16 + l15)*136 + 32*h;
    *(bf16x4*)(gr + 4*g)      = p0;
    *(bf16x4*)(gr + 16 + 4*g) = p1;
  }

  // hoist the wave's 4 WoF A-fragments; loads fly while other waves finish
  f32x4 wf[4];
  #pragma unroll
  for (int kt = 0; kt < 4; ++kt)
    wf[kt] = *(const f32x4*)(WoF + ((size_t)(w*4 + kt)*64 + lane)*8);
  #pragma unroll
  for (int kt = 0; kt < 4; ++kt)
    asm volatile("" : "+v"(wf[kt]));

  __syncthreads();

  // phase 2: out = gs @ Wo + bo. wave w -> output cols 16w..16w+15
  const int col = 16*w + 4*g;
  const float4 bb = *(const float4*)(bo + col);
  for (int nt = 0; nt < 8; ++nt) {
    bf16x8 bfr[4];
    #pragma unroll
    for (int kt = 0; kt < 4; ++kt)
      bfr[kt] = *(const bf16x8*)(gs + (size_t)(16*nt + l15)*136 + 32*kt + 8*g);
    f32x4 a0 = z;
    #pragma unroll
    for (int kt = 0; kt < 4; ++kt)
      a0 = MFMA(__builtin_bit_cast(bf16x8, wf[kt]), bfr[kt], a0);
    const int pos = rb + hf*128 + 16*nt + l15;
    *(float4*)(out + (size_t)pos*128 + col) =
        make_float4(a0[0] + bb.x, a0[1] + bb.y, a0[2] + bb.z, a0[3] + bb.w);
  }
}

// ---------------------------------------------------------------------------
extern "C" void kernel_launch(void* const* d_in, const int* in_sizes, int n_in,
                              void* d_out, int out_size, void* d_ws, size_t ws_size,
                              hipStream_t stream) {
  const float* pr    = (const float*)d_in[0];
  const float* mask  = (const float*)d_in[1];
  const float* gamma = (const float*)d_in[2];
  const float* beta  = (const float*)d_in[3];
  const float* Wq    = (const float*)d_in[4];
  const float* Wk    = (const float*)d_in[5];
  const float* Wv    = (const float*)d_in[6];
  const float* Wb    = (const float*)d_in[7];
  const float* Wfu   = (const float*)d_in[8];
  const float* bfu   = (const float*)d_in[9];
  const float* Wo    = (const float*)d_in[10];
  const float* bo    = (const float*)d_in[11];
  float* out = (float*)d_out;

  bf16* qbh = (bf16*)d_ws;                        // H*P*32
  bf16* kbh = qbh + (size_t)H * P * 32;
  bf16* vbh = kbh + (size_t)H * P * 32;
  bf16* gfb = vbh + (size_t)H * P * 32;           // P*128
  bf16* aob = gfb + (size_t)P * 128;              // H*P*32 (unused now)
  bf16* T5  = aob + (size_t)H * P * 32;           // H*P
  bf16* WF  = T5  + (size_t)H * P;                // 4*16384
  bf16* WoF = WF  + 4 * 16384;                    // 16384
  bf16* WbF = WoF + 16384;                        // 2048
  float* pb = (float*)(WbF + 2048);               // P*4 fp32

  k_prep<<<41, 256, 0, stream>>>(Wq, Wk, Wv, Wfu, Wo, Wb, WF, WoF, WbF);
  k_ln_proj<<<1024, 512, 0, stream>>>(pr, gamma, beta, bfu, WF, WbF,
                                      qbh, kbh, vbh, gfb, pb);
  k_bias<<<256, 256, 0, stream>>>(mask, pb, T5);
  k_attn_gate<<<512, 512, 0, stream>>>(qbh, kbh, vbh, T5, gfb, WoF, bo, out);
}